// Round 10
// baseline (189.356 us; speedup 1.0000x reference)
//
#include <hip/hip_runtime.h>
#include <math.h>

#define Bn 2
#define Hn 12
#define Tn 512
#define Cn 768
#define HS 64
#define BH 24
#define MTOP 8
#define NCOMB 36
#define NEGV -1e30f

typedef __bf16 bf16x8 __attribute__((ext_vector_type(8)));
typedef float f32x4 __attribute__((ext_vector_type(4)));

__device__ __constant__ int C_SL0[NCOMB] = {
  0,1,2,3,4,5,6,7,
  0,0,0,0,0,0,0,
  1,1,1,1,1,1,
  2,2,2,2,2,
  3,3,3,3,
  4,4,4,
  5,5,
  6};
__device__ __constant__ int C_SL1[NCOMB] = {
  -1,-1,-1,-1,-1,-1,-1,-1,
  1,2,3,4,5,6,7,
  2,3,4,5,6,7,
  3,4,5,6,7,
  4,5,6,7,
  5,6,7,
  6,7,
  7};

__device__ __constant__ int PA[45] = {
  0,0,0,0,0,0,0,0,0,
  1,1,1,1,1,1,1,1,
  2,2,2,2,2,2,2,
  3,3,3,3,3,3,
  4,4,4,4,4,
  5,5,5,5,
  6,6,6,
  7,7,
  8};
__device__ __constant__ int PB[45] = {
  0,1,2,3,4,5,6,7,8,
  1,2,3,4,5,6,7,8,
  2,3,4,5,6,7,8,
  3,4,5,6,7,8,
  4,5,6,7,8,
  5,6,7,8,
  6,7,8,
  7,8,
  8};

// lower-triangle 8x8 tile enumeration (ti >= tj)
__device__ __constant__ int TI[36] = {
  0,1,1,2,2,2,3,3,3,3,4,4,4,4,4,5,5,5,5,5,5,6,6,6,6,6,6,6,7,7,7,7,7,7,7,7};
__device__ __constant__ int TJ[36] = {
  0,0,1,0,1,2,0,1,2,3,0,1,2,3,4,0,1,2,3,4,5,0,1,2,3,4,5,6,0,1,2,3,4,5,6,7};

__device__ __forceinline__ unsigned short bf_rne(float x) {
    unsigned u = __float_as_uint(x);
    return (unsigned short)((u + 0x7fff + ((u >> 16) & 1)) >> 16);
}
__device__ __forceinline__ float bf_f(unsigned short s) {
    return __uint_as_float(((unsigned)s) << 16);
}

// ---- fp32 -> concatenated hi/hi/lo bf16 layout (row stride 2304) ---------------------
__global__ __launch_bounds__(256) void conv_cat(const float* __restrict__ s,
                                                unsigned short* __restrict__ dst,
                                                int n, int hiOff2, int loOff) {
    int idx = blockIdx.x * 256 + threadIdx.x;
    if (idx < n) {
        int r = idx / Cn, c = idx - r * Cn;
        float x = s[idx];
        unsigned short h = bf_rne(x);
        unsigned short l = bf_rne(x - bf_f(h));
        size_t base = (size_t)r * 2304 + c;
        dst[base] = h;
        dst[base + hiOff2] = h;
        dst[base + loOff] = l;
    }
}

__global__ __launch_bounds__(256) void conv_bf(const float* __restrict__ s,
                                               unsigned short* __restrict__ d, int n) {
    int idx = blockIdx.x * 256 + threadIdx.x;
    if (idx < n) d[idx] = bf_rne(s[idx]);
}

// ---- shared LDS-staged double-buffered bf16 NT GEMM core -----------------------------
__device__ __forceinline__ void gemm_core(const unsigned short* __restrict__ Ag,
                                          const unsigned short* __restrict__ Bg,
                                          int K, int NS,
                                          unsigned short* Ab, unsigned short* Bb,
                                          f32x4 acc[2][2]) {
    const int tid = threadIdx.x;
    const int wv = tid >> 6, lane = tid & 63;
    const int r0 = tid >> 3;
    const int c8 = (tid & 7) * 8;
    const int m0w = (wv >> 1) * 32;
    const int n0w = (wv & 1) * 32;
    const int fr = lane & 15;
    const int fk = (lane >> 4) * 8;

    const unsigned short* pa0 = Ag + (size_t)r0 * K + c8;
    const unsigned short* pa1 = Ag + (size_t)(r0 + 32) * K + c8;
    const unsigned short* pb0 = Bg + (size_t)r0 * K + c8;
    const unsigned short* pb1 = Bg + (size_t)(r0 + 32) * K + c8;

    bf16x8 ra0 = *(const bf16x8*)pa0;
    bf16x8 ra1 = *(const bf16x8*)pa1;
    bf16x8 rb0 = *(const bf16x8*)pb0;
    bf16x8 rb1 = *(const bf16x8*)pb1;

    const int sO = r0 * 72 + c8;
    for (int s = 0; s < NS; ++s) {
        const int bufo = (s & 1) * 4608;
        *(bf16x8*)(Ab + bufo + sO) = ra0;
        *(bf16x8*)(Ab + bufo + sO + 32 * 72) = ra1;
        *(bf16x8*)(Bb + bufo + sO) = rb0;
        *(bf16x8*)(Bb + bufo + sO + 32 * 72) = rb1;
        __syncthreads();
        if (s + 1 < NS) {
            ra0 = *(const bf16x8*)(pa0 + (s + 1) * 64);
            ra1 = *(const bf16x8*)(pa1 + (s + 1) * 64);
            rb0 = *(const bf16x8*)(pb0 + (s + 1) * 64);
            rb1 = *(const bf16x8*)(pb1 + (s + 1) * 64);
        }
        #pragma unroll
        for (int ks = 0; ks < 2; ++ks) {
            bf16x8 af[2], bg[2];
            #pragma unroll
            for (int mi = 0; mi < 2; ++mi)
                af[mi] = *(const bf16x8*)(Ab + bufo + (m0w + 16 * mi + fr) * 72 + ks * 32 + fk);
            #pragma unroll
            for (int ni = 0; ni < 2; ++ni)
                bg[ni] = *(const bf16x8*)(Bb + bufo + (n0w + 16 * ni + fr) * 72 + ks * 32 + fk);
            #pragma unroll
            for (int mi = 0; mi < 2; ++mi)
                #pragma unroll
                for (int ni = 0; ni < 2; ++ni)
                    acc[mi][ni] = __builtin_amdgcn_mfma_f32_16x16x32_bf16(af[mi], bg[ni], acc[mi][ni], 0, 0, 0);
        }
    }
}

// ---- qkv: C = xcat @ Wcat^T + bias (K'=2304 = 3-term split GEMM) ---------------------
__global__ __launch_bounds__(256) void mfma_qkv(const unsigned short* __restrict__ xcat,
                                                const unsigned short* __restrict__ Wcat,
                                                const float* __restrict__ bias,
                                                unsigned short* __restrict__ qcat,
                                                unsigned short* __restrict__ kcat,
                                                float* __restrict__ vh) {
    __shared__ unsigned short Ab[2 * 64 * 72];
    __shared__ unsigned short Bb[2 * 64 * 72];
    const int tm = blockIdx.x * 64;
    const int tn = blockIdx.y * 64;
    f32x4 acc[2][2] = {};
    gemm_core(xcat + (size_t)tm * 2304, Wcat + (size_t)tn * 2304, 2304, 36, Ab, Bb, acc);

    const int wv = threadIdx.x >> 6, lane = threadIdx.x & 63;
    const int kq = lane >> 4, r = lane & 15;
    const int part = tn / Cn;
    #pragma unroll
    for (int mi = 0; mi < 2; ++mi) {
        #pragma unroll
        for (int ni = 0; ni < 2; ++ni) {
            #pragma unroll
            for (int rr = 0; rr < 4; ++rr) {
                int mm = tm + (wv >> 1) * 32 + mi * 16 + kq * 4 + rr;
                int nn = tn + (wv & 1) * 32 + ni * 16 + r;
                float val = acc[mi][ni][rr] + bias[nn];
                int bb = mm >> 9, t = mm & 511;
                int c = nn - part * Cn;
                int h = c >> 6, d = c & 63;
                int bh = bb * Hn + h;
                if (part == 2) {
                    vh[((size_t)bh * Tn + t) * HS + d] = val;
                } else {
                    unsigned short s1 = bf_rne(val);
                    float r1 = val - bf_f(s1);
                    unsigned short s2 = bf_rne(r1);
                    unsigned short s3 = bf_rne(r1 - bf_f(s2));
                    size_t base = ((size_t)bh * Tn + t) * 384 + d;
                    if (part == 0) {   // qcat = [q1|q1|q2|q1|q3|q2]
                        qcat[base]       = s1;
                        qcat[base + 64]  = s1;
                        qcat[base + 192] = s1;
                        qcat[base + 128] = s2;
                        qcat[base + 320] = s2;
                        qcat[base + 256] = s3;
                    } else {           // kcat = [k1|k2|k1|k3|k1|k2]
                        kcat[base]       = s1;
                        kcat[base + 128] = s1;
                        kcat[base + 256] = s1;
                        kcat[base + 64]  = s2;
                        kcat[base + 320] = s2;
                        kcat[base + 192] = s3;
                    }
                }
            }
        }
    }
}

// ---- sim: S = qcat @ kcat^T per bh (K'=384 = 6-term split), triangle tiles -----------
__global__ __launch_bounds__(256) void mfma_sim(const unsigned short* __restrict__ qcat,
                                                const unsigned short* __restrict__ kcat,
                                                float* __restrict__ S) {
    __shared__ unsigned short Ab[2 * 64 * 72];
    __shared__ unsigned short Bb[2 * 64 * 72];
    const int bh = blockIdx.y;
    const int ti = TI[blockIdx.x], tj = TJ[blockIdx.x];
    f32x4 acc[2][2] = {};
    gemm_core(qcat + ((size_t)bh * Tn + ti * 64) * 384,
              kcat + ((size_t)bh * Tn + tj * 64) * 384, 384, 6, Ab, Bb, acc);

    const int wv = threadIdx.x >> 6, lane = threadIdx.x & 63;
    const int kq = lane >> 4, r = lane & 15;
    float* Sp = S + (size_t)bh * 147456 + (size_t)(ti * (ti + 1) / 2 + tj) * 4096;
    #pragma unroll
    for (int mi = 0; mi < 2; ++mi)
        #pragma unroll
        for (int ni = 0; ni < 2; ++ni)
            #pragma unroll
            for (int rr = 0; rr < 4; ++rr) {
                int ml = (wv >> 1) * 32 + mi * 16 + kq * 4 + rr;
                int nl = (wv & 1) * 32 + ni * 16 + r;
                Sp[ml * 64 + nl] = acc[mi][ni][rr];
            }
}

// ---- proj: out = ybf @ Wpbf^T + bias (K=768) -----------------------------------------
__global__ __launch_bounds__(256) void mfma_proj(const unsigned short* __restrict__ Abf,
                                                 const unsigned short* __restrict__ Bbf,
                                                 const float* __restrict__ bias,
                                                 float* __restrict__ outp) {
    __shared__ unsigned short Ab[2 * 64 * 72];
    __shared__ unsigned short Bb[2 * 64 * 72];
    const int tm = blockIdx.x * 64;
    const int tn = blockIdx.y * 64;
    f32x4 acc[2][2] = {};
    gemm_core(Abf + (size_t)tm * Cn, Bbf + (size_t)tn * Cn, Cn, 12, Ab, Bb, acc);

    const int wv = threadIdx.x >> 6, lane = threadIdx.x & 63;
    const int kq = lane >> 4, r = lane & 15;
    #pragma unroll
    for (int mi = 0; mi < 2; ++mi)
        #pragma unroll
        for (int ni = 0; ni < 2; ++ni)
            #pragma unroll
            for (int rr = 0; rr < 4; ++rr) {
                int mm = tm + (wv >> 1) * 32 + mi * 16 + kq * 4 + rr;
                int nn = tn + (wv & 1) * 32 + ni * 16 + r;
                outp[(size_t)mm * Cn + nn] = acc[mi][ni][rr] + bias[nn];
            }
}

// ---- DPP selection: TWO tokens per wave (interleaved chains for latency ILP) ---------
// Each wave handles tokens ibase, ibase+1; the two serial top-k/softmax chains are
// independent and interleave stage-by-stage, halving latency-bound time.
__global__ __launch_bounds__(256) void dpp_kernel(const float* __restrict__ S,
                                                  const unsigned short* __restrict__ kcat,
                                                  const float* __restrict__ vh,
                                                  unsigned short* __restrict__ yb) {
    const int bh = blockIdx.x;
    const int w = threadIdx.x >> 6;
    const int lane = threadIdx.x & 63;
    const int ibase = blockIdx.y * 8 + w * 2;

    __shared__ float KshW[8][9][68];   // 19584 B
    __shared__ float VshW[8][9][65];   // 18720 B
    __shared__ float Gsh[8][81];       //  2592 B
    __shared__ float qdsh[8][12];      //   384 B
    __shared__ float PWsh[8][36][4];   //  4608 B  -> ~45.9 KB total

    const float* Sbh = S + (size_t)bh * 147456;
    const unsigned short* kc = kcat + (size_t)bh * Tn * 384;
    const float* vbase = vh + (size_t)bh * Tn * HS;

    int ii[2], tib[2];
    float sv[2][8];
    #pragma unroll
    for (int tt = 0; tt < 2; ++tt) {
        const int i = ibase + tt;
        ii[tt] = i;
        const int t8 = i >> 6;
        tib[tt] = t8;
        const int tribase = t8 * (t8 + 1) / 2;
        const int rloc = (i & 63) * 64;
        #pragma unroll
        for (int rr = 0; rr < 8; ++rr) {
            sv[tt][rr] = -INFINITY;
            if (rr <= t8) {
                int j = rr * 64 + lane;
                float s = Sbh[(size_t)(tribase + rr) * 4096 + rloc + lane];
                sv[tt][rr] = (j <= i) ? s : -INFINITY;
            }
        }
    }

    // qd0 = sim[i][i]
    float qd0[2] = {0.f, 0.f};
    #pragma unroll
    for (int c = 0; c < 8; ++c)
        #pragma unroll
        for (int tt = 0; tt < 2; ++tt) {
            float t = __shfl(sv[tt][c], ii[tt] & 63, 64);
            if (c == tib[tt]) qd0[tt] = t;
        }

    // top-8: 8 passes, two interleaved butterflies (value desc, tie -> lower index)
    float topv[2][8]; int topi[2][8];
    #pragma unroll
    for (int p = 0; p < MTOP; ++p) {
        float bv[2]; int bi[2];
        #pragma unroll
        for (int tt = 0; tt < 2; ++tt) {
            bv[tt] = -INFINITY; bi[tt] = 0x7fffffff;
            #pragma unroll
            for (int r = 0; r < 8; ++r) {
                int j = r * 64 + lane;
                float v = sv[tt][r];
                if (v > bv[tt] || (v == bv[tt] && j < bi[tt])) { bv[tt] = v; bi[tt] = j; }
            }
        }
        #pragma unroll
        for (int off = 32; off > 0; off >>= 1)
            #pragma unroll
            for (int tt = 0; tt < 2; ++tt) {
                float ov = __shfl_xor(bv[tt], off, 64);
                int   oi = __shfl_xor(bi[tt], off, 64);
                if (ov > bv[tt] || (ov == bv[tt] && oi < bi[tt])) { bv[tt] = ov; bi[tt] = oi; }
            }
        #pragma unroll
        for (int tt = 0; tt < 2; ++tt) {
            topv[tt][p] = bv[tt]; topi[tt][p] = bi[tt];
            const int rs = bi[tt] >> 6, ls = bi[tt] & 63;
            #pragma unroll
            for (int r = 0; r < 8; ++r)
                if (r == rs && lane == ls) sv[tt][r] = -INFINITY;
        }
    }

    // stage K/V rows for both contexts (interleaved loads -> more in flight)
    #pragma unroll
    for (int tt = 0; tt < 2; ++tt) {
        const int ctx = w * 2 + tt;
        #pragma unroll
        for (int a = 0; a < 9; ++a) {
            int t = (a == 0) ? ii[tt] : topi[tt][a - 1];
            size_t kb = (size_t)t * 384 + lane;
            KshW[ctx][a][lane] = bf_f(kc[kb]) + bf_f(kc[kb + 64]) + bf_f(kc[kb + 192]);
            VshW[ctx][a][lane] = vbase[(size_t)t * HS + lane];
        }
        if (lane < 9) {
            float val = qd0[tt];
            #pragma unroll
            for (int p = 0; p < 8; ++p) if (lane == p + 1) val = topv[tt][p];
            qdsh[ctx][lane] = val;
        }
    }

    // gram for both contexts: lane l < 45 computes pair (PA[l], PB[l])
    if (lane < 45) {
        const int a = PA[lane], b = PB[lane];
        #pragma unroll
        for (int tt = 0; tt < 2; ++tt) {
            const int ctx = w * 2 + tt;
            const float4* rka = (const float4*)&KshW[ctx][a][0];
            const float4* rkb = (const float4*)&KshW[ctx][b][0];
            float acc = 0.f;
            #pragma unroll
            for (int t = 0; t < 16; ++t) {
                float4 fa = rka[t], fb = rkb[t];
                acc += fa.x * fb.x; acc += fa.y * fb.y;
                acc += fa.z * fb.z; acc += fa.w * fb.w;
            }
            Gsh[ctx][a * 9 + b] = acc;
            Gsh[ctx][b * 9 + a] = acc;
        }
    }

    // combos + softmax + PW for both contexts (independent; shuffles interleave)
    float score[2]; int ca[2], cb[2], sdim[2];
    #pragma unroll
    for (int tt = 0; tt < 2; ++tt) {
        const int ctx = w * 2 + tt;
        const int i = ii[tt];
        const int n_cand = (i + 1 < MTOP) ? (i + 1) : MTOP;
        int vmask = 0;
        #pragma unroll
        for (int s = 0; s < MTOP; ++s)
            if (s < n_cand && topi[tt][s] != i) vmask |= (1 << s);

        score[tt] = -INFINITY; ca[tt] = 0; cb[tt] = 0; sdim[tt] = 1;
        if (lane < NCOMB) {
            const int sl0 = C_SL0[lane], sl1 = C_SL1[lane];
            sdim[tt] = (sl1 < 0) ? 1 : 2;
            ca[tt] = sl0 + 1;
            cb[tt] = (sl1 < 0) ? 0 : sl1 + 1;
            bool valid = ((vmask >> sl0) & 1);
            if (sdim[tt] == 2) valid = valid && ((vmask >> sl1) & 1);
            float G00 = Gsh[ctx][0];
            float Gaa = Gsh[ctx][ca[tt] * 9 + ca[tt]];
            float G0a = Gsh[ctx][ca[tt]];
            float det;
            if (sdim[tt] == 1) {
                det = G00 * Gaa - G0a * G0a;
            } else {
                float G0b = Gsh[ctx][cb[tt]];
                float Gab = Gsh[ctx][ca[tt] * 9 + cb[tt]];
                float Gbb = Gsh[ctx][cb[tt] * 9 + cb[tt]];
                det = G00 * (Gaa * Gbb - Gab * Gab)
                    - G0a * (G0a * Gbb - Gab * G0b)
                    + G0b * (G0a * Gab - Gaa * G0b);
            }
            score[tt] = valid ? (logf(det + 1e-6f) / (float)(sdim[tt] + 1)) : NEGV;
        }
    }

    float mx[2] = {score[0], score[1]};
    #pragma unroll
    for (int off = 32; off > 0; off >>= 1)
        #pragma unroll
        for (int tt = 0; tt < 2; ++tt)
            mx[tt] = fmaxf(mx[tt], __shfl_xor(mx[tt], off, 64));
    float ee[2];
    #pragma unroll
    for (int tt = 0; tt < 2; ++tt)
        ee[tt] = (lane < NCOMB) ? expf(score[tt] - mx[tt]) : 0.f;
    float sum[2] = {ee[0], ee[1]};
    #pragma unroll
    for (int off = 32; off > 0; off >>= 1)
        #pragma unroll
        for (int tt = 0; tt < 2; ++tt)
            sum[tt] += __shfl_xor(sum[tt], off, 64);

    #pragma unroll
    for (int tt = 0; tt < 2; ++tt) {
        const int ctx = w * 2 + tt;
        if (lane < NCOMB) {
            float prob = ee[tt] / sum[tt];
            float d0 = qdsh[ctx][0]       * 0.125f;
            float d1 = qdsh[ctx][ca[tt]]  * 0.125f;
            float d2 = (sdim[tt] == 2) ? qdsh[ctx][cb[tt]] * 0.125f : -INFINITY;
            float m2 = fmaxf(fmaxf(d0, d1), d2);
            float e0 = expf(d0 - m2), e1 = expf(d1 - m2);
            float e2 = (sdim[tt] == 2) ? expf(d2 - m2) : 0.f;
            float inv = prob / (e0 + e1 + e2);
            float4 pw = {e0 * inv, e1 * inv, e2 * inv, 0.f};
            *(float4*)&PWsh[ctx][lane][0] = pw;
        }
    }

    // y for both contexts
    #pragma unroll
    for (int tt = 0; tt < 2; ++tt) {
        const int ctx = w * 2 + tt;
        const bool hasValid = (mx[tt] > -1e29f);
        const float v0 = VshW[ctx][0][lane];
        float y;
        if (!hasValid) {
            y = v0;
        } else {
            float acc = 0.f;
            #pragma unroll
            for (int c = 0; c < NCOMB; ++c) {
                float4 pw = *(const float4*)&PWsh[ctx][c][0];
                int a = C_SL0[c] + 1;
                int b = (C_SL1[c] < 0) ? 0 : C_SL1[c] + 1;
                acc += pw.x * v0 + pw.y * VshW[ctx][a][lane] + pw.z * VshW[ctx][b][lane];
            }
            y = acc;
        }
        const int bb = bh / Hn, h = bh % Hn;
        yb[((size_t)(bb * Tn + ii[tt])) * Cn + h * HS + lane] = bf_rne(y);
    }
}

extern "C" void kernel_launch(void* const* d_in, const int* in_sizes, int n_in,
                              void* d_out, int out_size, void* d_ws, size_t ws_size,
                              hipStream_t stream) {
    const float* x      = (const float*)d_in[0];
    const float* W_attn = (const float*)d_in[1];
    const float* b_attn = (const float*)d_in[2];
    const float* W_proj = (const float*)d_in[3];
    const float* b_proj = (const float*)d_in[4];
    float* out = (float*)d_out;

    char* ws = (char*)d_ws;
    float* vh            = (float*)(ws);                          //  0        3 MB
    unsigned short* qcat = (unsigned short*)(ws + 3145728);       //  3 MB     9 MB
    unsigned short* kcat = (unsigned short*)(ws + 12582912);      // 12 MB     9 MB
    unsigned short* xcat = (unsigned short*)(ws + 22020096);      // 21 MB     4.5 MB (dead after qkv)
    unsigned short* Wcat = (unsigned short*)(ws + 26738688);      // 25.5 MB  10.125 MB (dead after qkv)
    float* S             = (float*)(ws + 26738688);               // overlays Wcat, 13.5 MB
    unsigned short* ybf  = xcat;                                  // overlays xcat after qkv
    unsigned short* Wpbf = (unsigned short*)(ws + 40894464);      // 39 MB     1.125 MB -> 40.1 MB total

    const int NX = Bn * Tn * Cn;   // 786432
    const int NW = 3 * Cn * Cn;    // 1769472
    const int NP = Cn * Cn;        // 589824

    // 1) split-convert into concatenated-K layouts
    conv_cat<<<dim3((NX + 255) / 256), 256, 0, stream>>>(x, xcat, NX, 768, 1536);
    conv_cat<<<dim3((NW + 255) / 256), 256, 0, stream>>>(W_attn, Wcat, NW, 1536, 768);

    // 2) qkv as ONE bf16 GEMM, K'=2304; scatter epilogue
    mfma_qkv<<<dim3(16, 36), 256, 0, stream>>>(xcat, Wcat, b_attn, qcat, kcat, vh);

    // 3) S = qcat @ kcat^T (K'=384, 6-term split), lower-triangle tiles, packed store
    mfma_sim<<<dim3(36, BH), 256, 0, stream>>>(qcat, kcat, S);

    // 4) W_proj -> bf16
    conv_bf<<<dim3((NP + 255) / 256), 256, 0, stream>>>(W_proj, Wpbf, NP);

    // 5) dpp: TWO tokens per wave (8 per block), latency chains interleaved
    dpp_kernel<<<dim3(BH, Tn / 8), 256, 0, stream>>>(S, kcat, vh, ybf);

    // 6) out = y @ Wp^T + bias
    mfma_proj<<<dim3(16, 12), 256, 0, stream>>>(ybf, Wpbf, b_proj, out);
}

// Round 11
// 182.863 us; speedup vs baseline: 1.0355x; 1.0355x over previous
//
#include <hip/hip_runtime.h>
#include <math.h>

#define Bn 2
#define Hn 12
#define Tn 512
#define Cn 768
#define HS 64
#define BH 24
#define MTOP 8
#define NCOMB 36
#define NEGV -1e30f

typedef __bf16 bf16x8 __attribute__((ext_vector_type(8)));
typedef float f32x4 __attribute__((ext_vector_type(4)));

__device__ __constant__ int C_SL0[NCOMB] = {
  0,1,2,3,4,5,6,7,
  0,0,0,0,0,0,0,
  1,1,1,1,1,1,
  2,2,2,2,2,
  3,3,3,3,
  4,4,4,
  5,5,
  6};
__device__ __constant__ int C_SL1[NCOMB] = {
  -1,-1,-1,-1,-1,-1,-1,-1,
  1,2,3,4,5,6,7,
  2,3,4,5,6,7,
  3,4,5,6,7,
  4,5,6,7,
  5,6,7,
  6,7,
  7};

__device__ __constant__ int PA[45] = {
  0,0,0,0,0,0,0,0,0,
  1,1,1,1,1,1,1,1,
  2,2,2,2,2,2,2,
  3,3,3,3,3,3,
  4,4,4,4,4,
  5,5,5,5,
  6,6,6,
  7,7,
  8};
__device__ __constant__ int PB[45] = {
  0,1,2,3,4,5,6,7,8,
  1,2,3,4,5,6,7,8,
  2,3,4,5,6,7,8,
  3,4,5,6,7,8,
  4,5,6,7,8,
  5,6,7,8,
  6,7,8,
  7,8,
  8};

// lower-triangle 8x8 tile enumeration (ti >= tj)
__device__ __constant__ int TI[36] = {
  0,1,1,2,2,2,3,3,3,3,4,4,4,4,4,5,5,5,5,5,5,6,6,6,6,6,6,6,7,7,7,7,7,7,7,7};
__device__ __constant__ int TJ[36] = {
  0,0,1,0,1,2,0,1,2,3,0,1,2,3,4,0,1,2,3,4,5,0,1,2,3,4,5,6,0,1,2,3,4,5,6,7};

__device__ __forceinline__ unsigned short bf_rne(float x) {
    unsigned u = __float_as_uint(x);
    return (unsigned short)((u + 0x7fff + ((u >> 16) & 1)) >> 16);
}
__device__ __forceinline__ float bf_f(unsigned short s) {
    return __uint_as_float(((unsigned)s) << 16);
}

// ---- fp32 -> concatenated hi/hi/lo bf16 layout (row stride 2304) ---------------------
__global__ __launch_bounds__(256) void conv_cat(const float* __restrict__ s,
                                                unsigned short* __restrict__ dst,
                                                int n, int hiOff2, int loOff) {
    int idx = blockIdx.x * 256 + threadIdx.x;
    if (idx < n) {
        int r = idx / Cn, c = idx - r * Cn;
        float x = s[idx];
        unsigned short h = bf_rne(x);
        unsigned short l = bf_rne(x - bf_f(h));
        size_t base = (size_t)r * 2304 + c;
        dst[base] = h;
        dst[base + hiOff2] = h;
        dst[base + loOff] = l;
    }
}

__global__ __launch_bounds__(256) void conv_bf(const float* __restrict__ s,
                                               unsigned short* __restrict__ d, int n) {
    int idx = blockIdx.x * 256 + threadIdx.x;
    if (idx < n) d[idx] = bf_rne(s[idx]);
}

// ---- shared LDS-staged double-buffered bf16 NT GEMM core -----------------------------
// Kst = row stride (elems); extent = NS*64 <= Kst.
__device__ __forceinline__ void gemm_core(const unsigned short* __restrict__ Ag,
                                          const unsigned short* __restrict__ Bg,
                                          int Kst, int NS,
                                          unsigned short* Ab, unsigned short* Bb,
                                          f32x4 acc[2][2]) {
    const int tid = threadIdx.x;
    const int wv = tid >> 6, lane = tid & 63;
    const int r0 = tid >> 3;
    const int c8 = (tid & 7) * 8;
    const int m0w = (wv >> 1) * 32;
    const int n0w = (wv & 1) * 32;
    const int fr = lane & 15;
    const int fk = (lane >> 4) * 8;

    const unsigned short* pa0 = Ag + (size_t)r0 * Kst + c8;
    const unsigned short* pa1 = Ag + (size_t)(r0 + 32) * Kst + c8;
    const unsigned short* pb0 = Bg + (size_t)r0 * Kst + c8;
    const unsigned short* pb1 = Bg + (size_t)(r0 + 32) * Kst + c8;

    bf16x8 ra0 = *(const bf16x8*)pa0;
    bf16x8 ra1 = *(const bf16x8*)pa1;
    bf16x8 rb0 = *(const bf16x8*)pb0;
    bf16x8 rb1 = *(const bf16x8*)pb1;

    const int sO = r0 * 72 + c8;
    for (int s = 0; s < NS; ++s) {
        const int bufo = (s & 1) * 4608;
        *(bf16x8*)(Ab + bufo + sO) = ra0;
        *(bf16x8*)(Ab + bufo + sO + 32 * 72) = ra1;
        *(bf16x8*)(Bb + bufo + sO) = rb0;
        *(bf16x8*)(Bb + bufo + sO + 32 * 72) = rb1;
        __syncthreads();
        if (s + 1 < NS) {
            ra0 = *(const bf16x8*)(pa0 + (s + 1) * 64);
            ra1 = *(const bf16x8*)(pa1 + (s + 1) * 64);
            rb0 = *(const bf16x8*)(pb0 + (s + 1) * 64);
            rb1 = *(const bf16x8*)(pb1 + (s + 1) * 64);
        }
        #pragma unroll
        for (int ks = 0; ks < 2; ++ks) {
            bf16x8 af[2], bg[2];
            #pragma unroll
            for (int mi = 0; mi < 2; ++mi)
                af[mi] = *(const bf16x8*)(Ab + bufo + (m0w + 16 * mi + fr) * 72 + ks * 32 + fk);
            #pragma unroll
            for (int ni = 0; ni < 2; ++ni)
                bg[ni] = *(const bf16x8*)(Bb + bufo + (n0w + 16 * ni + fr) * 72 + ks * 32 + fk);
            #pragma unroll
            for (int mi = 0; mi < 2; ++mi)
                #pragma unroll
                for (int ni = 0; ni < 2; ++ni)
                    acc[mi][ni] = __builtin_amdgcn_mfma_f32_16x16x32_bf16(af[mi], bg[ni], acc[mi][ni], 0, 0, 0);
        }
    }
}

// ---- qkv fused: by<24 -> q/k 3-term GEMM (K'=2304); by>=24 -> v 1-term (K=768) -------
__global__ __launch_bounds__(256) void mfma_qkv(const unsigned short* __restrict__ xcat,
                                                const unsigned short* __restrict__ Wcat,
                                                const float* __restrict__ bias,
                                                unsigned short* __restrict__ qcat,
                                                unsigned short* __restrict__ kcat,
                                                float* __restrict__ vh) {
    __shared__ unsigned short Ab[2 * 64 * 72];
    __shared__ unsigned short Bb[2 * 64 * 72];
    const int tm = blockIdx.x * 64;
    const int by = blockIdx.y;
    const int wv = threadIdx.x >> 6, lane = threadIdx.x & 63;
    const int kq = lane >> 4, r = lane & 15;
    f32x4 acc[2][2] = {};

    if (by < 24) {
        const int tn = by * 64;
        gemm_core(xcat + (size_t)tm * 2304, Wcat + (size_t)tn * 2304, 2304, 36, Ab, Bb, acc);
        const int part = tn / Cn;          // 0=q, 1=k
        #pragma unroll
        for (int mi = 0; mi < 2; ++mi) {
            #pragma unroll
            for (int ni = 0; ni < 2; ++ni) {
                #pragma unroll
                for (int rr = 0; rr < 4; ++rr) {
                    int mm = tm + (wv >> 1) * 32 + mi * 16 + kq * 4 + rr;
                    int nn = tn + (wv & 1) * 32 + ni * 16 + r;
                    float val = acc[mi][ni][rr] + bias[nn];
                    int bb = mm >> 9, t = mm & 511;
                    int c = nn - part * Cn;
                    int h = c >> 6, d = c & 63;
                    int bh = bb * Hn + h;
                    unsigned short s1 = bf_rne(val);
                    float r1 = val - bf_f(s1);
                    unsigned short s2 = bf_rne(r1);
                    unsigned short s3 = bf_rne(r1 - bf_f(s2));
                    size_t base = ((size_t)bh * Tn + t) * 384 + d;
                    if (part == 0) {   // qcat = [q1|q1|q2|q1|q3|q2]
                        qcat[base]       = s1;
                        qcat[base + 64]  = s1;
                        qcat[base + 192] = s1;
                        qcat[base + 128] = s2;
                        qcat[base + 320] = s2;
                        qcat[base + 256] = s3;
                    } else {           // kcat = [k1|k2|k1|k3|k1|k2]
                        kcat[base]       = s1;
                        kcat[base + 128] = s1;
                        kcat[base + 256] = s1;
                        kcat[base + 64]  = s2;
                        kcat[base + 320] = s2;
                        kcat[base + 192] = s3;
                    }
                }
            }
        }
    } else {
        // v: single-term bf16 (xhi @ Wvhi^T), K extent 768 within stride-2304 rows
        const int hvi = by - 24;           // head-col tile 0..11
        const int cv = hvi * 64;
        gemm_core(xcat + (size_t)tm * 2304,
                  Wcat + (size_t)(1536 + cv) * 2304, 2304, 12, Ab, Bb, acc);
        #pragma unroll
        for (int mi = 0; mi < 2; ++mi) {
            #pragma unroll
            for (int ni = 0; ni < 2; ++ni) {
                #pragma unroll
                for (int rr = 0; rr < 4; ++rr) {
                    int mm = tm + (wv >> 1) * 32 + mi * 16 + kq * 4 + rr;
                    int nloc = (wv & 1) * 32 + ni * 16 + r;      // 0..63 == d
                    float val = acc[mi][ni][rr] + bias[1536 + cv + nloc];
                    int bb = mm >> 9, t = mm & 511;
                    int bh = bb * Hn + hvi;
                    vh[((size_t)bh * Tn + t) * HS + nloc] = val;
                }
            }
        }
    }
}

// ---- sim: S = qcat @ kcat^T per bh (K'=384 = 6-term split), triangle tiles -----------
__global__ __launch_bounds__(256) void mfma_sim(const unsigned short* __restrict__ qcat,
                                                const unsigned short* __restrict__ kcat,
                                                float* __restrict__ S) {
    __shared__ unsigned short Ab[2 * 64 * 72];
    __shared__ unsigned short Bb[2 * 64 * 72];
    const int bh = blockIdx.y;
    const int ti = TI[blockIdx.x], tj = TJ[blockIdx.x];
    f32x4 acc[2][2] = {};
    gemm_core(qcat + ((size_t)bh * Tn + ti * 64) * 384,
              kcat + ((size_t)bh * Tn + tj * 64) * 384, 384, 6, Ab, Bb, acc);

    const int wv = threadIdx.x >> 6, lane = threadIdx.x & 63;
    const int kq = lane >> 4, r = lane & 15;
    float* Sp = S + (size_t)bh * 147456 + (size_t)(ti * (ti + 1) / 2 + tj) * 4096;
    #pragma unroll
    for (int mi = 0; mi < 2; ++mi)
        #pragma unroll
        for (int ni = 0; ni < 2; ++ni)
            #pragma unroll
            for (int rr = 0; rr < 4; ++rr) {
                int ml = (wv >> 1) * 32 + mi * 16 + kq * 4 + rr;
                int nl = (wv & 1) * 32 + ni * 16 + r;
                Sp[ml * 64 + nl] = acc[mi][ni][rr];
            }
}

// ---- proj: out = ybf @ Wpbf^T + bias (K=768) -----------------------------------------
__global__ __launch_bounds__(256) void mfma_proj(const unsigned short* __restrict__ Abf,
                                                 const unsigned short* __restrict__ Bbf,
                                                 const float* __restrict__ bias,
                                                 float* __restrict__ outp) {
    __shared__ unsigned short Ab[2 * 64 * 72];
    __shared__ unsigned short Bb[2 * 64 * 72];
    const int tm = blockIdx.x * 64;
    const int tn = blockIdx.y * 64;
    f32x4 acc[2][2] = {};
    gemm_core(Abf + (size_t)tm * Cn, Bbf + (size_t)tn * Cn, Cn, 12, Ab, Bb, acc);

    const int wv = threadIdx.x >> 6, lane = threadIdx.x & 63;
    const int kq = lane >> 4, r = lane & 15;
    #pragma unroll
    for (int mi = 0; mi < 2; ++mi)
        #pragma unroll
        for (int ni = 0; ni < 2; ++ni)
            #pragma unroll
            for (int rr = 0; rr < 4; ++rr) {
                int mm = tm + (wv >> 1) * 32 + mi * 16 + kq * 4 + rr;
                int nn = tn + (wv & 1) * 32 + ni * 16 + r;
                outp[(size_t)mm * Cn + nn] = acc[mi][ni][rr] + bias[nn];
            }
}

// ---- DPP selection: TWO tokens per wave; coef-collapsed epilogue ---------------------
__global__ __launch_bounds__(256) void dpp_kernel(const float* __restrict__ S,
                                                  const unsigned short* __restrict__ kcat,
                                                  const float* __restrict__ vh,
                                                  unsigned short* __restrict__ yb) {
    const int bh = blockIdx.x;
    const int w = threadIdx.x >> 6;
    const int lane = threadIdx.x & 63;
    const int ibase = blockIdx.y * 8 + w * 2;

    __shared__ float KshW[8][9][68];   // 19584 B
    __shared__ float VshW[8][9][65];   // 18720 B
    __shared__ float Gsh[8][81];       //  2592 B
    __shared__ float qdsh[8][12];      //   384 B  -> 41280 B total
    const float* Sbh = S + (size_t)bh * 147456;
    const unsigned short* kc = kcat + (size_t)bh * Tn * 384;
    const float* vbase = vh + (size_t)bh * Tn * HS;

    int ii[2], tib[2];
    float sv[2][8];
    #pragma unroll
    for (int tt = 0; tt < 2; ++tt) {
        const int i = ibase + tt;
        ii[tt] = i;
        const int t8 = i >> 6;
        tib[tt] = t8;
        const int tribase = t8 * (t8 + 1) / 2;
        const int rloc = (i & 63) * 64;
        #pragma unroll
        for (int rr = 0; rr < 8; ++rr) {
            sv[tt][rr] = -INFINITY;
            if (rr <= t8) {
                int j = rr * 64 + lane;
                float s = Sbh[(size_t)(tribase + rr) * 4096 + rloc + lane];
                sv[tt][rr] = (j <= i) ? s : -INFINITY;
            }
        }
    }

    // qd0 = sim[i][i]
    float qd0[2] = {0.f, 0.f};
    #pragma unroll
    for (int c = 0; c < 8; ++c)
        #pragma unroll
        for (int tt = 0; tt < 2; ++tt) {
            float t = __shfl(sv[tt][c], ii[tt] & 63, 64);
            if (c == tib[tt]) qd0[tt] = t;
        }

    // top-8: 8 passes, two interleaved butterflies (value desc, tie -> lower index)
    float topv[2][8]; int topi[2][8];
    #pragma unroll
    for (int p = 0; p < MTOP; ++p) {
        float bv[2]; int bi[2];
        #pragma unroll
        for (int tt = 0; tt < 2; ++tt) {
            bv[tt] = -INFINITY; bi[tt] = 0x7fffffff;
            #pragma unroll
            for (int r = 0; r < 8; ++r) {
                int j = r * 64 + lane;
                float v = sv[tt][r];
                if (v > bv[tt] || (v == bv[tt] && j < bi[tt])) { bv[tt] = v; bi[tt] = j; }
            }
        }
        #pragma unroll
        for (int off = 32; off > 0; off >>= 1)
            #pragma unroll
            for (int tt = 0; tt < 2; ++tt) {
                float ov = __shfl_xor(bv[tt], off, 64);
                int   oi = __shfl_xor(bi[tt], off, 64);
                if (ov > bv[tt] || (ov == bv[tt] && oi < bi[tt])) { bv[tt] = ov; bi[tt] = oi; }
            }
        #pragma unroll
        for (int tt = 0; tt < 2; ++tt) {
            topv[tt][p] = bv[tt]; topi[tt][p] = bi[tt];
            const int rs = bi[tt] >> 6, ls = bi[tt] & 63;
            #pragma unroll
            for (int r = 0; r < 8; ++r)
                if (r == rs && lane == ls) sv[tt][r] = -INFINITY;
        }
    }

    // stage K/V rows for both contexts
    #pragma unroll
    for (int tt = 0; tt < 2; ++tt) {
        const int ctx = w * 2 + tt;
        #pragma unroll
        for (int a = 0; a < 9; ++a) {
            int t = (a == 0) ? ii[tt] : topi[tt][a - 1];
            size_t kb = (size_t)t * 384 + lane;
            KshW[ctx][a][lane] = bf_f(kc[kb]) + bf_f(kc[kb + 64]) + bf_f(kc[kb + 192]);
            VshW[ctx][a][lane] = vbase[(size_t)t * HS + lane];
        }
        if (lane < 9) {
            float val = qd0[tt];
            #pragma unroll
            for (int p = 0; p < 8; ++p) if (lane == p + 1) val = topv[tt][p];
            qdsh[ctx][lane] = val;
        }
    }

    // gram for both contexts
    if (lane < 45) {
        const int a = PA[lane], b = PB[lane];
        #pragma unroll
        for (int tt = 0; tt < 2; ++tt) {
            const int ctx = w * 2 + tt;
            const float4* rka = (const float4*)&KshW[ctx][a][0];
            const float4* rkb = (const float4*)&KshW[ctx][b][0];
            float acc = 0.f;
            #pragma unroll
            for (int t = 0; t < 16; ++t) {
                float4 fa = rka[t], fb = rkb[t];
                acc += fa.x * fb.x; acc += fa.y * fb.y;
                acc += fa.z * fb.z; acc += fa.w * fb.w;
            }
            Gsh[ctx][a * 9 + b] = acc;
            Gsh[ctx][b * 9 + a] = acc;
        }
    }

    // combos (lanes 0..35)
    const int sl0c = (lane < NCOMB) ? C_SL0[lane] : -1;
    const int sl1c = (lane < NCOMB) ? C_SL1[lane] : -1;
    float score[2]; int ca[2], cb[2], sdim[2];
    #pragma unroll
    for (int tt = 0; tt < 2; ++tt) {
        const int ctx = w * 2 + tt;
        const int i = ii[tt];
        const int n_cand = (i + 1 < MTOP) ? (i + 1) : MTOP;
        int vmask = 0;
        #pragma unroll
        for (int s = 0; s < MTOP; ++s)
            if (s < n_cand && topi[tt][s] != i) vmask |= (1 << s);

        score[tt] = -INFINITY; ca[tt] = 0; cb[tt] = 0; sdim[tt] = 1;
        if (lane < NCOMB) {
            sdim[tt] = (sl1c < 0) ? 1 : 2;
            ca[tt] = sl0c + 1;
            cb[tt] = (sl1c < 0) ? 0 : sl1c + 1;
            bool valid = ((vmask >> sl0c) & 1);
            if (sdim[tt] == 2) valid = valid && ((vmask >> sl1c) & 1);
            float G00 = Gsh[ctx][0];
            float Gaa = Gsh[ctx][ca[tt] * 9 + ca[tt]];
            float G0a = Gsh[ctx][ca[tt]];
            float det;
            if (sdim[tt] == 1) {
                det = G00 * Gaa - G0a * G0a;
            } else {
                float G0b = Gsh[ctx][cb[tt]];
                float Gab = Gsh[ctx][ca[tt] * 9 + cb[tt]];
                float Gbb = Gsh[ctx][cb[tt] * 9 + cb[tt]];
                det = G00 * (Gaa * Gbb - Gab * Gab)
                    - G0a * (G0a * Gbb - Gab * G0b)
                    + G0b * (G0a * Gab - Gaa * G0b);
            }
            score[tt] = valid ? (logf(det + 1e-6f) / (float)(sdim[tt] + 1)) : NEGV;
        }
    }

    float mx[2] = {score[0], score[1]};
    #pragma unroll
    for (int off = 32; off > 0; off >>= 1)
        #pragma unroll
        for (int tt = 0; tt < 2; ++tt)
            mx[tt] = fmaxf(mx[tt], __shfl_xor(mx[tt], off, 64));
    float ee[2];
    #pragma unroll
    for (int tt = 0; tt < 2; ++tt)
        ee[tt] = (lane < NCOMB) ? expf(score[tt] - mx[tt]) : 0.f;
    float sum[2] = {ee[0], ee[1]};
    #pragma unroll
    for (int off = 32; off > 0; off >>= 1)
        #pragma unroll
        for (int tt = 0; tt < 2; ++tt)
            sum[tt] += __shfl_xor(sum[tt], off, 64);

    // per-lane prob-folded attention weights
    float pwx[2] = {0.f, 0.f}, pwy[2] = {0.f, 0.f}, pwz[2] = {0.f, 0.f};
    #pragma unroll
    for (int tt = 0; tt < 2; ++tt) {
        const int ctx = w * 2 + tt;
        if (lane < NCOMB) {
            float prob = ee[tt] / sum[tt];
            float d0 = qdsh[ctx][0]      * 0.125f;
            float d1 = qdsh[ctx][ca[tt]] * 0.125f;
            float d2 = (sdim[tt] == 2) ? qdsh[ctx][cb[tt]] * 0.125f : -INFINITY;
            float m2 = fmaxf(fmaxf(d0, d1), d2);
            float e0 = expf(d0 - m2), e1 = expf(d1 - m2);
            float e2 = (sdim[tt] == 2) ? expf(d2 - m2) : 0.f;
            float inv = prob / (e0 + e1 + e2);
            pwx[tt] = e0 * inv; pwy[tt] = e1 * inv; pwz[tt] = e2 * inv;
        }
    }

    // coefficient collapse: y = c0*V0 + sum_s cs[s]*V[s+1]
    // 18 independent butterfly sums (9 coefs x 2 ctx) -> high ILP, no PW LDS round-trip
    float c0[2]; float cs[2][8];
    #pragma unroll
    for (int tt = 0; tt < 2; ++tt) {
        c0[tt] = pwx[tt];
        #pragma unroll
        for (int s = 0; s < 8; ++s)
            cs[tt][s] = ((sl0c == s) ? pwy[tt] : 0.f) + ((sl1c == s) ? pwz[tt] : 0.f);
    }
    #pragma unroll
    for (int off = 32; off > 0; off >>= 1) {
        #pragma unroll
        for (int tt = 0; tt < 2; ++tt) {
            c0[tt] += __shfl_xor(c0[tt], off, 64);
            #pragma unroll
            for (int s = 0; s < 8; ++s)
                cs[tt][s] += __shfl_xor(cs[tt][s], off, 64);
        }
    }

    // y for both contexts (9 LDS b32 reads each)
    #pragma unroll
    for (int tt = 0; tt < 2; ++tt) {
        const int ctx = w * 2 + tt;
        const bool hasValid = (mx[tt] > -1e29f);
        const float v0 = VshW[ctx][0][lane];
        float y = v0;
        if (hasValid) {
            y = c0[tt] * v0;
            #pragma unroll
            for (int s = 0; s < 8; ++s)
                y += cs[tt][s] * VshW[ctx][s + 1][lane];
        }
        const int bb = bh / Hn, h = bh % Hn;
        yb[((size_t)(bb * Tn + ii[tt])) * Cn + h * HS + lane] = bf_rne(y);
    }
}

extern "C" void kernel_launch(void* const* d_in, const int* in_sizes, int n_in,
                              void* d_out, int out_size, void* d_ws, size_t ws_size,
                              hipStream_t stream) {
    const float* x      = (const float*)d_in[0];
    const float* W_attn = (const float*)d_in[1];
    const float* b_attn = (const float*)d_in[2];
    const float* W_proj = (const float*)d_in[3];
    const float* b_proj = (const float*)d_in[4];
    float* out = (float*)d_out;

    char* ws = (char*)d_ws;
    float* vh            = (float*)(ws);                          //  0        3 MB
    unsigned short* qcat = (unsigned short*)(ws + 3145728);       //  3 MB     9 MB
    unsigned short* kcat = (unsigned short*)(ws + 12582912);      // 12 MB     9 MB
    unsigned short* xcat = (unsigned short*)(ws + 22020096);      // 21 MB     4.5 MB (dead after qkv)
    unsigned short* Wcat = (unsigned short*)(ws + 26738688);      // 25.5 MB  10.125 MB (dead after qkv)
    float* S             = (float*)(ws + 26738688);               // overlays Wcat, 13.5 MB
    unsigned short* ybf  = xcat;                                  // overlays xcat after qkv
    unsigned short* Wpbf = (unsigned short*)(ws + 40894464);      // 39 MB     1.125 MB -> 40.1 MB total

    const int NX = Bn * Tn * Cn;   // 786432
    const int NW = 3 * Cn * Cn;    // 1769472
    const int NP = Cn * Cn;        // 589824

    // 1) split-convert into concatenated-K layouts
    conv_cat<<<dim3((NX + 255) / 256), 256, 0, stream>>>(x, xcat, NX, 768, 1536);
    conv_cat<<<dim3((NW + 255) / 256), 256, 0, stream>>>(W_attn, Wcat, NW, 1536, 768);

    // 2) fused qkv: q/k 3-term (by<24) + v 1-term (by>=24)
    mfma_qkv<<<dim3(16, 36), 256, 0, stream>>>(xcat, Wcat, b_attn, qcat, kcat, vh);

    // 3) S = qcat @ kcat^T (K'=384, 6-term split), lower-triangle tiles, packed store
    mfma_sim<<<dim3(36, BH), 256, 0, stream>>>(qcat, kcat, S);

    // 4) W_proj -> bf16
    conv_bf<<<dim3((NP + 255) / 256), 256, 0, stream>>>(W_proj, Wpbf, NP);

    // 5) dpp: two tokens per wave, coef-collapsed epilogue
    dpp_kernel<<<dim3(BH, Tn / 8), 256, 0, stream>>>(S, kcat, vh, ybf);

    // 6) out = y @ Wp^T + bias
    mfma_proj<<<dim3(16, 12), 256, 0, stream>>>(ybf, Wpbf, b_proj, out);
}